// Round 5
// baseline (143.039 us; speedup 1.0000x reference)
//
#include <hip/hip_runtime.h>

// PrototypeTripletRankingLoss: B=1024, K=127, D=512, fp32.
// loss = mean_b mean_k max(0, 0.2 + cos(ref_b, neg_bk) - cos(ref_b, pos_b))
// with each norm clamped to >= 1e-8 (torch cosine_similarity semantics).
//
// R4 = R3 with the compile fix: __builtin_nontemporal_load requires a native
// vector type, not HIP_vector_type<float,4>. Use ext_vector_type(4).
//
// Structure: single kernel + last-block-done final reduction. Ticket counter
// in d_ws, zeroed each call via 4-byte hipMemsetAsync (d_ws is poisoned 0xAA
// before timing). neg read exactly once -> nontemporal loads. Final mean
// reads partials in fixed order -> deterministic regardless of block order.

#define NB 1024
#define NK 127
#define ND 512
#define MARGIN 0.2f
#define CEPS 1e-8f

typedef float floatx4 __attribute__((ext_vector_type(4)));

__device__ __forceinline__ float dot4(const floatx4 a, const floatx4 b) {
    return a.x * b.x + a.y * b.y + a.z * b.z + a.w * b.w;
}

__device__ __forceinline__ void load8nt(floatx4 (&n)[8], const float* __restrict__ p) {
    #pragma unroll
    for (int j = 0; j < 8; ++j)
        n[j] = __builtin_nontemporal_load((const floatx4*)(p + j * 64));
}

// Reduce one 4-k group: dot+sumsq over 16-lane subgroups, relu-accumulate.
__device__ __forceinline__ void reduce_group(
    const floatx4 (&r)[8], const floatx4 (&n)[8], bool valid,
    float inv_r, float pos_sim, float& acc)
{
    float nd = 0.0f, ns = 0.0f;
    #pragma unroll
    for (int j = 0; j < 8; ++j) {
        nd += dot4(r[j], n[j]);
        ns += dot4(n[j], n[j]);
    }
    #pragma unroll
    for (int off = 1; off <= 8; off <<= 1) {
        nd += __shfl_xor(nd, off);
        ns += __shfl_xor(ns, off);
    }
    const float sim = nd * inv_r * (1.0f / fmaxf(sqrtf(ns), CEPS));
    acc += valid ? fmaxf(MARGIN + sim - pos_sim, 0.0f) : 0.0f;
}

__global__ __launch_bounds__(256, 4) void triplet_fused(
    const float* __restrict__ ref, const float* __restrict__ pos,
    const float* __restrict__ neg, float* __restrict__ partial,
    unsigned* __restrict__ counter, float* __restrict__ out)
{
    const int b    = blockIdx.x;
    const int tid  = threadIdx.x;
    const int wave = tid >> 6;
    const int lane = tid & 63;
    const int sub  = lane >> 4;   // which of 4 k's in the group
    const int sl   = lane & 15;   // 16 lanes per k; lane owns floats [sl*4 + j*64]

    const float* refr = ref + (size_t)b * ND;
    const float* posr = pos + (size_t)b * ND;

    floatx4 r[8];
    #pragma unroll
    for (int j = 0; j < 8; ++j) r[j] = *(const floatx4*)(refr + sl * 4 + j * 64);

    float rs = 0.0f, ps = 0.0f, pd = 0.0f;
    #pragma unroll
    for (int j = 0; j < 8; ++j) {
        const floatx4 p = *(const floatx4*)(posr + sl * 4 + j * 64);
        rs += dot4(r[j], r[j]);
        ps += dot4(p, p);
        pd += dot4(r[j], p);
    }
    #pragma unroll
    for (int off = 1; off <= 8; off <<= 1) {
        rs += __shfl_xor(rs, off);
        ps += __shfl_xor(ps, off);
        pd += __shfl_xor(pd, off);
    }
    const float inv_r   = 1.0f / fmaxf(sqrtf(rs), CEPS);
    const float pos_sim = pd * inv_r * (1.0f / fmaxf(sqrtf(ps), CEPS));

    const float* negb = neg + (size_t)b * (NK * ND);

    // Wave w handles groups g = w + 4*it, it = 0..7. k = 4g + sub (k=127 masked).
    // Double-buffered nontemporal loads: next group's 8 float4 issued before
    // the current group's butterfly chain.
    float acc = 0.0f;
    floatx4 bufA[8], bufB[8];

    auto gaddr = [&](int it) -> const float* {
        const int k  = 4 * (wave + 4 * it) + sub;
        const int kk = (k < NK) ? k : (NK - 1);
        return negb + (size_t)kk * ND + sl * 4;
    };
    auto gvalid = [&](int it) -> bool {
        return 4 * (wave + 4 * it) + sub < NK;
    };

    load8nt(bufA, gaddr(0));
    #pragma unroll
    for (int p2 = 0; p2 < 4; ++p2) {
        const int it = 2 * p2;
        load8nt(bufB, gaddr(it + 1));
        reduce_group(r, bufA, gvalid(it), inv_r, pos_sim, acc);
        if (p2 < 3) load8nt(bufA, gaddr(it + 2));
        reduce_group(r, bufB, gvalid(it + 1), inv_r, pos_sim, acc);
    }

    // acc identical across the 16 lanes of each quarter; sum the 4 quarters.
    acc += __shfl_xor(acc, 16);
    acc += __shfl_xor(acc, 32);

    __shared__ float sacc[4];
    if (lane == 0) sacc[wave] = acc;
    __syncthreads();

    // Publish partial, then draw a ticket (device scope).
    __shared__ bool amLast;
    if (tid == 0) {
        const float total = (sacc[0] + sacc[1]) + (sacc[2] + sacc[3]);
        __hip_atomic_store(&partial[b], total, __ATOMIC_RELEASE,
                           __HIP_MEMORY_SCOPE_AGENT);
        const unsigned t = __hip_atomic_fetch_add(counter, 1u, __ATOMIC_ACQ_REL,
                                                  __HIP_MEMORY_SCOPE_AGENT);
        amLast = (t == NB - 1);
    }
    __syncthreads();

    if (amLast) {
        __threadfence();   // acquire: make all blocks' partials visible
        float s = 0.0f;
        for (int i = tid; i < NB; i += 256)
            s += __hip_atomic_load(&partial[i], __ATOMIC_RELAXED,
                                   __HIP_MEMORY_SCOPE_AGENT);
        #pragma unroll
        for (int off = 32; off; off >>= 1) s += __shfl_xor(s, off);
        __shared__ float w[4];
        if (lane == 0) w[wave] = s;
        __syncthreads();
        if (tid == 0)
            out[0] = ((w[0] + w[1]) + (w[2] + w[3])) * (1.0f / ((float)NB * (float)NK));
    }
}

extern "C" void kernel_launch(void* const* d_in, const int* in_sizes, int n_in,
                              void* d_out, int out_size, void* d_ws, size_t ws_size,
                              hipStream_t stream) {
    const float* ref = (const float*)d_in[0];
    const float* pos = (const float*)d_in[1];
    const float* neg = (const float*)d_in[2];
    float* out = (float*)d_out;

    unsigned* counter = (unsigned*)d_ws;                      // 4 B ticket
    float*    partial = (float*)((char*)d_ws + 256);          // NB floats

    (void)hipMemsetAsync(counter, 0, sizeof(unsigned), stream);  // graph-capturable
    triplet_fused<<<NB, 256, 0, stream>>>(ref, pos, neg, partial, counter, out);
}

// Round 6
// 105.705 us; speedup vs baseline: 1.3532x; 1.3532x over previous
//
#include <hip/hip_runtime.h>

// PrototypeTripletRankingLoss: B=1024, K=127, D=512, fp32.
// loss = mean_b mean_k max(0, 0.2 + cos(ref_b, neg_bk) - cos(ref_b, pos_b))
// with each norm clamped to >= 1e-8 (torch cosine_similarity semantics).
//
// R6 = R0's measured-best main loop (48.0 us: per-block row, 4 waves strided
// over k, full-wave butterfly; no prefetch buffers, no nontemporal, no
// min-waves launch_bounds -> no VGPR cap, no spill) + last-block-done final
// reduction to remove the serialized second dispatch (~4-5 us).
// R5's 3x regression: launch_bounds(256,4) VGPR cap + 96 regs of double
// buffers => scratch spill (~0.5 GB extra traffic). Both reverted.
//
// Ticket counter lives in d_ws, zeroed each call by a 4-byte hipMemsetAsync
// (graph-capturable; d_ws is poisoned 0xAA once before timing). The block
// drawing the last ticket sums all 1024 partials in fixed order ->
// bitwise-deterministic output regardless of block completion order.

#define NB 1024
#define NK 127
#define ND 512
#define MARGIN 0.2f
#define CEPS 1e-8f

__device__ __forceinline__ float dot4(const float4 a, const float4 b) {
    return a.x * b.x + a.y * b.y + a.z * b.z + a.w * b.w;
}

__global__ __launch_bounds__(256) void triplet_fused(
    const float* __restrict__ ref, const float* __restrict__ pos,
    const float* __restrict__ neg, float* __restrict__ partial,
    unsigned* __restrict__ counter, float* __restrict__ out)
{
    const int b    = blockIdx.x;
    const int tid  = threadIdx.x;
    const int wave = tid >> 6;
    const int lane = tid & 63;

    const float* refr = ref + (size_t)b * ND;
    const float* posr = pos + (size_t)b * ND;

    const float4 r0 = *(const float4*)(refr + lane * 4);
    const float4 r1 = *(const float4*)(refr + 256 + lane * 4);
    const float4 p0 = *(const float4*)(posr + lane * 4);
    const float4 p1 = *(const float4*)(posr + 256 + lane * 4);

    float rs = dot4(r0, r0) + dot4(r1, r1);   // ||ref||^2 partial
    float ps = dot4(p0, p0) + dot4(p1, p1);   // ||pos||^2 partial
    float pd = dot4(r0, p0) + dot4(r1, p1);   // ref.pos partial

    #pragma unroll
    for (int off = 32; off; off >>= 1) {
        rs += __shfl_xor(rs, off);
        ps += __shfl_xor(ps, off);
        pd += __shfl_xor(pd, off);
    }

    const float inv_r   = 1.0f / fmaxf(sqrtf(rs), CEPS);
    const float pos_sim = pd * inv_r * (1.0f / fmaxf(sqrtf(ps), CEPS));

    float acc = 0.0f;
    const float* negb = neg + (size_t)b * (NK * ND);
    for (int k = wave; k < NK; k += 4) {
        const float* nr = negb + (size_t)k * ND;
        const float4 n0 = *(const float4*)(nr + lane * 4);
        const float4 n1 = *(const float4*)(nr + 256 + lane * 4);
        float nd = dot4(r0, n0) + dot4(r1, n1);
        float ns = dot4(n0, n0) + dot4(n1, n1);
        #pragma unroll
        for (int off = 32; off; off >>= 1) {
            nd += __shfl_xor(nd, off);
            ns += __shfl_xor(ns, off);
        }
        const float sim = nd * inv_r * (1.0f / fmaxf(sqrtf(ns), CEPS));
        acc += fmaxf(MARGIN + sim - pos_sim, 0.0f);
    }

    __shared__ float sacc[4];
    if (lane == 0) sacc[wave] = acc;
    __syncthreads();

    // Publish this block's partial, then draw a ticket (device scope).
    __shared__ bool amLast;
    if (tid == 0) {
        const float total = (sacc[0] + sacc[1]) + (sacc[2] + sacc[3]);
        __hip_atomic_store(&partial[b], total, __ATOMIC_RELEASE,
                           __HIP_MEMORY_SCOPE_AGENT);
        const unsigned t = __hip_atomic_fetch_add(counter, 1u, __ATOMIC_ACQ_REL,
                                                  __HIP_MEMORY_SCOPE_AGENT);
        amLast = (t == NB - 1);
    }
    __syncthreads();

    // Last block to finish: all partials are published (acquire via the
    // ticket RMW chain). Fixed-order sum -> deterministic.
    if (amLast) {
        __threadfence();
        float s = 0.0f;
        for (int i = tid; i < NB; i += 256)
            s += __hip_atomic_load(&partial[i], __ATOMIC_RELAXED,
                                   __HIP_MEMORY_SCOPE_AGENT);
        #pragma unroll
        for (int off = 32; off; off >>= 1) s += __shfl_xor(s, off);
        __shared__ float w[4];
        if (lane == 0) w[wave] = s;
        __syncthreads();
        if (tid == 0)
            out[0] = ((w[0] + w[1]) + (w[2] + w[3])) * (1.0f / ((float)NB * (float)NK));
    }
}

extern "C" void kernel_launch(void* const* d_in, const int* in_sizes, int n_in,
                              void* d_out, int out_size, void* d_ws, size_t ws_size,
                              hipStream_t stream) {
    const float* ref = (const float*)d_in[0];
    const float* pos = (const float*)d_in[1];
    const float* neg = (const float*)d_in[2];
    float* out = (float*)d_out;

    unsigned* counter = (unsigned*)d_ws;               // 4 B ticket
    float*    partial = (float*)((char*)d_ws + 256);   // NB floats

    (void)hipMemsetAsync(counter, 0, sizeof(unsigned), stream);
    triplet_fused<<<NB, 256, 0, stream>>>(ref, pos, neg, partial, counter, out);
}

// Round 7
// 56.765 us; speedup vs baseline: 2.5199x; 1.8622x over previous
//
#include <hip/hip_runtime.h>

// PrototypeTripletRankingLoss: B=1024, K=127, D=512, fp32.
// loss = mean_b mean_k max(0, 0.2 + cos(ref_b, neg_bk) - cos(ref_b, pos_b))
// with each norm clamped to >= 1e-8 (torch cosine_similarity semantics).
//
// R7: R0's measured-best main loop (48.0 us) with the pipelining made
// EXPLICIT (#pragma unroll 4 on the k-loop). R6's post-mortem: the same
// source compiled to 24 VGPRs with only one 32B load-pair in flight ->
// latency-bound collapse to 754 GB/s; R0's speed came from the compiler's
// implicit unroll, which R6's bulky tail disabled. Pin it with the pragma.
//
// Fusion tail is minimal: per-block atomicAdd of the scaled partial into
// out[0] (device-scope, relaxed; no fences, no ticket, no second kernel).
// fp32 ordering jitter ~5e-7 << 4e-3 threshold. d_out is zeroed by a 4-byte
// hipMemsetAsync at the stream head each call (d_out is poisoned 0xAA before
// timing and never re-zeroed between replays).

#define NB 1024
#define NK 127
#define ND 512
#define MARGIN 0.2f
#define CEPS 1e-8f

__device__ __forceinline__ float dot4(const float4 a, const float4 b) {
    return a.x * b.x + a.y * b.y + a.z * b.z + a.w * b.w;
}

__global__ __launch_bounds__(256) void triplet_fused(
    const float* __restrict__ ref, const float* __restrict__ pos,
    const float* __restrict__ neg, float* __restrict__ out)
{
    const int b    = blockIdx.x;
    const int tid  = threadIdx.x;
    const int wave = tid >> 6;
    const int lane = tid & 63;

    const float* refr = ref + (size_t)b * ND;
    const float* posr = pos + (size_t)b * ND;

    const float4 r0 = *(const float4*)(refr + lane * 4);
    const float4 r1 = *(const float4*)(refr + 256 + lane * 4);
    const float4 p0 = *(const float4*)(posr + lane * 4);
    const float4 p1 = *(const float4*)(posr + 256 + lane * 4);

    float rs = dot4(r0, r0) + dot4(r1, r1);   // ||ref||^2 partial
    float ps = dot4(p0, p0) + dot4(p1, p1);   // ||pos||^2 partial
    float pd = dot4(r0, p0) + dot4(r1, p1);   // ref.pos partial

    #pragma unroll
    for (int off = 32; off; off >>= 1) {
        rs += __shfl_xor(rs, off);
        ps += __shfl_xor(ps, off);
        pd += __shfl_xor(pd, off);
    }

    const float inv_r   = 1.0f / fmaxf(sqrtf(rs), CEPS);
    const float pos_sim = pd * inv_r * (1.0f / fmaxf(sqrtf(ps), CEPS));

    float acc = 0.0f;
    const float* negb = neg + (size_t)b * (NK * ND);
    #pragma unroll 4
    for (int k = wave; k < NK; k += 4) {
        const float* nr = negb + (size_t)k * ND;
        const float4 n0 = *(const float4*)(nr + lane * 4);
        const float4 n1 = *(const float4*)(nr + 256 + lane * 4);
        float nd = dot4(r0, n0) + dot4(r1, n1);
        float ns = dot4(n0, n0) + dot4(n1, n1);
        #pragma unroll
        for (int off = 32; off; off >>= 1) {
            nd += __shfl_xor(nd, off);
            ns += __shfl_xor(ns, off);
        }
        const float sim = nd * inv_r * (1.0f / fmaxf(sqrtf(ns), CEPS));
        acc += fmaxf(MARGIN + sim - pos_sim, 0.0f);
    }

    // Block tail: sum the 4 wave accumulators, one atomicAdd per block.
    __shared__ float sacc[4];
    if (lane == 0) sacc[wave] = acc;
    __syncthreads();
    if (tid == 0) {
        const float total = (sacc[0] + sacc[1]) + (sacc[2] + sacc[3]);
        atomicAdd(out, total * (1.0f / ((float)NB * (float)NK)));
    }
}

extern "C" void kernel_launch(void* const* d_in, const int* in_sizes, int n_in,
                              void* d_out, int out_size, void* d_ws, size_t ws_size,
                              hipStream_t stream) {
    const float* ref = (const float*)d_in[0];
    const float* pos = (const float*)d_in[1];
    const float* neg = (const float*)d_in[2];
    float* out = (float*)d_out;

    (void)hipMemsetAsync(out, 0, sizeof(float), stream);   // graph-capturable
    triplet_fused<<<NB, 256, 0, stream>>>(ref, pos, neg, out);
}

// Round 8
// 47.858 us; speedup vs baseline: 2.9888x; 1.1861x over previous
//
#include <hip/hip_runtime.h>

// PrototypeTripletRankingLoss: B=1024, K=127, D=512, fp32.
// loss = mean_b mean_k max(0, 0.2 + cos(ref_b, neg_bk) - cos(ref_b, pos_b))
// with each norm clamped to >= 1e-8 (torch cosine_similarity semantics).
//
// R8 = R0 VERBATIM (measured 48.0 us, best of 7 rounds). Main kernel runs at
// ~6.1 TB/s = 97% of the measured read ceiling (6.29 TB/s); the ~4.5 us
// second dispatch is the price of a deterministic final mean. All fusion
// attempts (cooperative, ticket, atomicAdd) regressed by perturbing the
// main loop's compiler-chosen load pipelining (R5: spill 143us, R6: 24-VGPR
// latency collapse 105us, R7: 56.8us). Do not touch the main loop.

#define NB 1024
#define NK 127
#define ND 512
#define MARGIN 0.2f
#define CEPS 1e-8f

__device__ __forceinline__ float dot4(const float4 a, const float4 b) {
    return a.x * b.x + a.y * b.y + a.z * b.z + a.w * b.w;
}

// One block per batch row. 256 threads = 4 waves; wave w handles k = w, w+4, ...
// Each lane owns 8 floats of the D=512 row: [lane*4 .. +3] and [256+lane*4 .. +3]
// (two fully-coalesced float4 loads per row).
__global__ __launch_bounds__(256) void triplet_main(
    const float* __restrict__ ref, const float* __restrict__ pos,
    const float* __restrict__ neg, float* __restrict__ partial)
{
    const int b    = blockIdx.x;
    const int tid  = threadIdx.x;
    const int wave = tid >> 6;
    const int lane = tid & 63;

    const float* refr = ref + (size_t)b * ND;
    const float* posr = pos + (size_t)b * ND;

    const float4 r0 = *(const float4*)(refr + lane * 4);
    const float4 r1 = *(const float4*)(refr + 256 + lane * 4);
    const float4 p0 = *(const float4*)(posr + lane * 4);
    const float4 p1 = *(const float4*)(posr + 256 + lane * 4);

    float rs = dot4(r0, r0) + dot4(r1, r1);   // ||ref||^2 partial
    float ps = dot4(p0, p0) + dot4(p1, p1);   // ||pos||^2 partial
    float pd = dot4(r0, p0) + dot4(r1, p1);   // ref.pos partial

    #pragma unroll
    for (int off = 32; off; off >>= 1) {
        rs += __shfl_xor(rs, off);
        ps += __shfl_xor(ps, off);
        pd += __shfl_xor(pd, off);
    }

    const float inv_r   = 1.0f / fmaxf(sqrtf(rs), CEPS);
    const float pos_sim = pd * inv_r * (1.0f / fmaxf(sqrtf(ps), CEPS));

    float acc = 0.0f;
    const float* negb = neg + (size_t)b * (NK * ND);
    for (int k = wave; k < NK; k += 4) {
        const float* nr = negb + (size_t)k * ND;
        const float4 n0 = *(const float4*)(nr + lane * 4);
        const float4 n1 = *(const float4*)(nr + 256 + lane * 4);
        float nd = dot4(r0, n0) + dot4(r1, n1);
        float ns = dot4(n0, n0) + dot4(n1, n1);
        #pragma unroll
        for (int off = 32; off; off >>= 1) {
            nd += __shfl_xor(nd, off);
            ns += __shfl_xor(ns, off);
        }
        const float sim = nd * inv_r * (1.0f / fmaxf(sqrtf(ns), CEPS));
        acc += fmaxf(MARGIN + sim - pos_sim, 0.0f);
    }

    // Block reduce the 4 wave accumulators (all lanes of a wave hold the same
    // butterfly-reduced values, so lane 0's acc is the wave total).
    __shared__ float sacc[4];
    if (lane == 0) sacc[wave] = acc;
    __syncthreads();
    if (tid == 0) partial[b] = (sacc[0] + sacc[1]) + (sacc[2] + sacc[3]);
}

// Deterministic final reduction: 1 block, 256 threads over 1024 partials.
__global__ __launch_bounds__(256) void triplet_reduce(
    const float* __restrict__ partial, float* __restrict__ out)
{
    float s = 0.0f;
    for (int i = threadIdx.x; i < NB; i += 256) s += partial[i];
    #pragma unroll
    for (int off = 32; off; off >>= 1) s += __shfl_xor(s, off);
    __shared__ float w[4];
    if ((threadIdx.x & 63) == 0) w[threadIdx.x >> 6] = s;
    __syncthreads();
    if (threadIdx.x == 0)
        out[0] = ((w[0] + w[1]) + (w[2] + w[3])) * (1.0f / ((float)NB * (float)NK));
}

extern "C" void kernel_launch(void* const* d_in, const int* in_sizes, int n_in,
                              void* d_out, int out_size, void* d_ws, size_t ws_size,
                              hipStream_t stream) {
    const float* ref = (const float*)d_in[0];
    const float* pos = (const float*)d_in[1];
    const float* neg = (const float*)d_in[2];
    float* out     = (float*)d_out;
    float* partial = (float*)d_ws;   // NB floats = 4 KiB scratch

    triplet_main<<<NB, 256, 0, stream>>>(ref, pos, neg, partial);
    triplet_reduce<<<1, 256, 0, stream>>>(partial, out);
}